// Round 7
// baseline (3453.076 us; speedup 1.0000x reference)
//
#include <hip/hip_runtime.h>

typedef __bf16 bf16x8 __attribute__((ext_vector_type(8)));
typedef float f32x4 __attribute__((ext_vector_type(4)));

__device__ __forceinline__ float sigmoidf_fast(float x) {
  return 1.f / (1.f + __expf(-x));
}
__device__ __forceinline__ float tanhf_fast(float x) {
  float e = __expf(2.f * x);
  return 1.f - 2.f / (e + 1.f);
}
__device__ __forceinline__ unsigned pack2(float a, float b) {
  unsigned short ua = __builtin_bit_cast(unsigned short, (__bf16)a);
  unsigned short ub = __builtin_bit_cast(unsigned short, (__bf16)b);
  return (unsigned)ua | ((unsigned)ub << 16);
}

// Wt[tap][oc][ci] = (bf16)W[oc][ci][tap], tap = ky*3+kx  (k-contiguous A rows)
__global__ void transpose_w_kernel(const float* __restrict__ Wsrc,
                                   __bf16* __restrict__ Wt, int C4, int C2) {
  int idx = blockIdx.x * 256 + threadIdx.x;
  int total = C4 * C2 * 9;
  if (idx >= total) return;
  int tap = idx / (C4 * C2);
  int rem = idx - tap * (C4 * C2);
  int oc = rem / C2;
  int ci = rem - oc * C2;
  Wt[idx] = (__bf16)Wsrc[(oc * C2 + ci) * 9 + tap];
}

__global__ void combine_kernel(const float* __restrict__ hf,
                               const float* __restrict__ hb,
                               float* __restrict__ out, int n) {
  int idx = blockIdx.x * 256 + threadIdx.x;
  if (idx >= n) return;
  out[idx] = (hf[idx] + hb[idx]) * 0.5f;
}

// LDS budget (target: 2 blocks/CU, <= 80 KB/block):
// level-1: sT 6*34*136*2 = 55488 + A sbuf 256*40*2      = 20480 -> 75968
// level-0: sT 4*66*72*2  = 38016 + A dbuf 2*256*40*2    = 40960 -> 78976
constexpr int SMEM_BYTES = 78976;

// Block = (dir d, 64-ch slice cs, batch b, OROWS rows). 8 waves = 2 N-groups
// (rg) x 4 c-waves (wvr); wave tile M=64 (4 gates x 16ch) x N=64 px.
// K split into 2 halves (x-channels, then h-channels); image window staged
// per half (halves the image LDS -> 2 blocks/CU). A prefetched to VGPRs
// during previous chunk's MFMAs; level-0 double-buffers the A slab.
template <int C, int H, int W, int OROWS, int DBUF>
__device__ __forceinline__ void convlstm_block(
    char* smem, const float* __restrict__ x_t, int maskv,
    const __bf16* __restrict__ Wt, const float* __restrict__ bias,
    const float* __restrict__ h_in, float* __restrict__ h_out,
    float* __restrict__ c_st, int d, int b, int y0, int cs)
{
  constexpr int Bz = 8, C2 = 2 * C, C4 = 4 * C;
  constexpr int COLS = W + 2;          // image x at slot x+1; 0, W+1 zero halo
  constexpr int C2p = C + 8;           // per-half ci leading dim (mult of 8)
  constexpr int IMR = OROWS + 2;
  constexpr int PLANE = H * W, CHW = C * PLANE;
  constexpr int AP = 40;               // A k-stride: 32 + 8 pad (2-way banks)
  constexpr int ABUF = 256 * AP;
  constexpr int CPT = C / 32;          // ci-chunks per tap per half
  constexpr int CPH = 9 * CPT;         // chunks per half
  constexpr int NCH = 2 * CPH;
  constexpr int CTPR = (W / 16) < 4 ? (W / 16) : 4;
  constexpr int RPG = OROWS / 2;
  constexpr int W4 = W / 4;
  constexpr int IMG_ITERS = (C / 4) * IMR * W / 512;
  constexpr int ITERS = 2;             // A stage: 256 rows * 4 parts / 512 thr

  __bf16* sT = (__bf16*)smem;
  __bf16* sA = (__bf16*)(smem + (size_t)IMR * COLS * C2p * 2);

  const int tid = threadIdx.x;
  const float* hin_b = h_in + (size_t)(d * Bz + b) * CHW;
  float* hout_b = h_out + (size_t)(d * Bz + b) * CHW;

  if (maskv <= 0) {
    // carry this block's 64 channels x OROWS rows (c in-place, untouched)
    for (int u = tid; u < 64 * OROWS * W4; u += 512) {
      int c = cs * 64 + u / (OROWS * W4);
      int rem = u % (OROWS * W4);
      int r = rem / W4, xu = rem % W4;
      size_t off = (size_t)c * PLANE + (size_t)(y0 + r) * W + xu * 4;
      *reinterpret_cast<float4*>(hout_b + off) =
          *reinterpret_cast<const float4*>(hin_b + off);
    }
    return;
  }

  const __bf16* Wtd = Wt + (size_t)d * (9 * C4 * C2);
  const float* x_b = x_t + (size_t)b * CHW;

  // per-thread A staging geometry: slab row aoc = g*64 + cl -> oc g*C+cs*64+cl
  int src_off[ITERS], dst_off[ITERS];
#pragma unroll
  for (int it = 0; it < ITERS; ++it) {
    int u = it * 512 + tid;
    int aoc = u >> 2, part = u & 3;
    int g = aoc >> 6, cl = aoc & 63;
    src_off[it] = (g * C + cs * 64 + cl) * C2 + part * 8;
    dst_off[it] = aoc * AP + part * 8;
  }

  uint4 aReg[ITERS];
  auto prefetchA = [&](int kc) {
    int half = kc / CPH, within = kc - half * CPH;
    int tap = within / CPT, ck = within - tap * CPT;
    size_t base = (size_t)tap * C4 * C2 + half * C + ck * 32;
#pragma unroll
    for (int it = 0; it < ITERS; ++it)
      aReg[it] = *reinterpret_cast<const uint4*>(Wtd + base + src_off[it]);
  };
  auto commitA = [&](int kc) {
    __bf16* dst = sA + (DBUF ? (kc & 1) * ABUF : 0);
#pragma unroll
    for (int it = 0; it < ITERS; ++it)
      *reinterpret_cast<uint4*>(dst + dst_off[it]) = aReg[it];
  };

  auto stage_image = [&](int half) {
    const float* srcp = half ? hin_b : x_b;
#pragma unroll
    for (int it = 0; it < IMG_ITERS; ++it) {
      int u = it * 512 + tid;
      int x = u % W;
      int t2 = u / W;
      int rr = t2 % IMR, ci = (t2 / IMR) * 4;
      int yy = y0 + rr - 1;
      uint2 pv; pv.x = 0u; pv.y = 0u;
      if (yy >= 0 && yy < H) {
        const float* s0 = srcp + (size_t)ci * PLANE + (size_t)yy * W + x;
        pv.x = pack2(s0[0], s0[PLANE]);
        pv.y = pack2(s0[2 * PLANE], s0[3 * PLANE]);
      }
      *reinterpret_cast<uint2*>(&sT[(rr * COLS + x + 1) * C2p + ci]) = pv;
    }
    for (int u = tid; u < (C / 4) * IMR * 2; u += 512) {
      int ci = (u / (IMR * 2)) * 4;
      int rem = u % (IMR * 2);
      int rr = rem >> 1;
      int slot = (rem & 1) ? (W + 1) : 0;
      uint2 z; z.x = 0u; z.y = 0u;
      *reinterpret_cast<uint2*>(&sT[(rr * COLS + slot) * C2p + ci]) = z;
    }
  };

  prefetchA(0);      // long-latency loads in flight during image staging
  stage_image(0);

  const int lane = tid & 63, wv = tid >> 6;
  const int rg = wv >> 2, wvr = wv & 3;
  const int n = lane & 15, q = lane >> 4;

  f32x4 acc[4][4];
  f32x4 zero = {0.f, 0.f, 0.f, 0.f};
#pragma unroll
  for (int g = 0; g < 4; ++g)
#pragma unroll
    for (int nt = 0; nt < 4; ++nt) acc[g][nt] = zero;

  for (int kc = 0; kc < NCH; ++kc) {
    if (!DBUF || kc == CPH) __syncthreads();  // end prev reads (sA and/or sT)
    if (kc == CPH) stage_image(1);            // swap to h-channel half
    commitA(kc);
    __syncthreads();
    if (kc + 1 < NCH) prefetchA(kc + 1);      // lands during MFMAs below

    const int half = kc / CPH, within = kc - half * CPH;
    const int tap = within / CPT, ck = within - tap * CPT;
    const int ky = tap / 3, kx = tap - 3 * ky;
    const int ci_off = ck * 32;
    const __bf16* sAb = sA + (DBUF ? (kc & 1) * ABUF : 0);

    bf16x8 bfr[4];
#pragma unroll
    for (int nt = 0; nt < 4; ++nt) {
      int row = rg * RPG + nt / CTPR + ky;
      int slot = (nt % CTPR) * 16 + n + kx;
      bfr[nt] = *reinterpret_cast<const bf16x8*>(
          &sT[(row * COLS + slot) * C2p + ci_off + q * 8]);
    }
    bf16x8 afr[4];
#pragma unroll
    for (int g = 0; g < 4; ++g)
      afr[g] = *reinterpret_cast<const bf16x8*>(
          &sAb[(g * 64 + wvr * 16 + n) * AP + q * 8]);
#pragma unroll
    for (int g = 0; g < 4; ++g)
#pragma unroll
      for (int nt = 0; nt < 4; ++nt)
        acc[g][nt] = __builtin_amdgcn_mfma_f32_16x16x32_bf16(
            afr[g], bfr[nt], acc[g][nt], 0, 0, 0);
  }

  // ---- fused LSTM gate epilogue (D: col = n = px, row = q*4+r = channel) ----
  float* c_b = c_st + (size_t)(d * Bz + b) * CHW;
#pragma unroll
  for (int r = 0; r < 4; ++r) {
    const int cg = cs * 64 + wvr * 16 + q * 4 + r;
    const float bi = bias[0 * C + cg];
    const float bff = bias[1 * C + cg];
    const float bo = bias[2 * C + cg];
    const float bg = bias[3 * C + cg];
#pragma unroll
    for (int nt = 0; nt < 4; ++nt) {
      const int y = y0 + rg * RPG + nt / CTPR;
      const int x = (nt % CTPR) * 16 + n;
      const size_t off = (size_t)cg * PLANE + (size_t)y * W + x;
      const float vi = acc[0][nt][r] + bi;
      const float vf = acc[1][nt][r] + bff;
      const float vo = acc[2][nt][r] + bo;
      const float vg = acc[3][nt][r] + bg;
      const float cn = sigmoidf_fast(vf) * c_b[off] + sigmoidf_fast(vi) * tanhf_fast(vg);
      c_b[off] = cn;
      hout_b[off] = sigmoidf_fast(vo) * tanhf_fast(cn);
    }
  }
}

// blocks [0,256) = level-1 (2 dir x 2 cs x 8 b x 8 yb; 2x work, scheduled
// first), [256,768) = level-0 (2 dir x 8 b x 32 yb). dir = lowest grid bit.
__global__ __launch_bounds__(512, 4)
void step_kernel(const float* __restrict__ x0, const float* __restrict__ x1,
                 const int* __restrict__ mask_t,
                 const __bf16* __restrict__ Wt0, const __bf16* __restrict__ Wt1,
                 const float* __restrict__ bf0, const float* __restrict__ bb0,
                 const float* __restrict__ bf1, const float* __restrict__ bb1,
                 const float* __restrict__ hin0, float* __restrict__ hout0,
                 float* __restrict__ c0,
                 const float* __restrict__ hin1, float* __restrict__ hout1,
                 float* __restrict__ c1)
{
  __shared__ __align__(16) char smem[SMEM_BYTES];
  const int idx = blockIdx.x;
  if (idx < 256) {
    int d = idx & 1, cs = (idx >> 1) & 1;
    int b = (idx >> 2) & 7, yb = idx >> 5;    // yb in [0,8): 4 rows each
    convlstm_block<128, 32, 32, 4, 0>(smem, x1, mask_t[b], Wt1,
        d == 0 ? bf1 : bb1, hin1, hout1, c1, d, b, yb * 4, cs);
  } else {
    int j = idx - 256;
    int d = j & 1, b = (j >> 1) & 7, yb = j >> 4;  // yb in [0,32): 2 rows each
    convlstm_block<64, 64, 64, 2, 1>(smem, x0, mask_t[b], Wt0,
        d == 0 ? bf0 : bb0, hin0, hout0, c0, d, b, yb * 2, 0);
  }
}

extern "C" void kernel_launch(void* const* d_in, const int* in_sizes, int n_in,
                              void* d_out, int out_size, void* d_ws, size_t ws_size,
                              hipStream_t stream) {
  const float* feat0 = (const float*)d_in[0];
  const float* feat1 = (const float*)d_in[1];
  const int* mask = (const int*)d_in[2];
  const float* Wf0 = (const float*)d_in[3];
  const float* bf0 = (const float*)d_in[4];
  const float* Wb0 = (const float*)d_in[5];
  const float* bb0 = (const float*)d_in[6];
  const float* Wf1 = (const float*)d_in[7];
  const float* bf1 = (const float*)d_in[8];
  const float* Wb1 = (const float*)d_in[9];
  const float* bb1 = (const float*)d_in[10];

  const int T = 16;
  const size_t SZ0 = (size_t)8 * 64 * 64 * 64;   // per-(dir,buf) h elems, level 0
  const size_t SZ1 = (size_t)8 * 128 * 32 * 32;  // level 1
  const size_t WT0 = (size_t)9 * 256 * 128;      // per-dir transposed weights
  const size_t WT1 = (size_t)9 * 512 * 256;

  char* p = (char*)d_ws;
  __bf16* Wt0 = (__bf16*)p; p += 2 * WT0 * sizeof(__bf16);
  __bf16* Wt1 = (__bf16*)p; p += 2 * WT1 * sizeof(__bf16);
  float* h0 = (float*)p;    p += 4 * SZ0 * sizeof(float);   // [buf][dir][B][C][H][W]
  float* h1 = (float*)p;    p += 4 * SZ1 * sizeof(float);
  float* c0 = (float*)p;    p += 2 * SZ0 * sizeof(float);   // [dir][B][C][H][W]
  float* c1 = (float*)p;    p += 2 * SZ1 * sizeof(float);

  hipMemsetAsync(h0, 0, 2 * SZ0 * sizeof(float), stream);
  hipMemsetAsync(h1, 0, 2 * SZ1 * sizeof(float), stream);
  hipMemsetAsync(c0, 0, 2 * SZ0 * sizeof(float), stream);
  hipMemsetAsync(c1, 0, 2 * SZ1 * sizeof(float), stream);

  transpose_w_kernel<<<((int)WT0 + 255) / 256, 256, 0, stream>>>(Wf0, Wt0, 256, 128);
  transpose_w_kernel<<<((int)WT0 + 255) / 256, 256, 0, stream>>>(Wb0, Wt0 + WT0, 256, 128);
  transpose_w_kernel<<<((int)WT1 + 255) / 256, 256, 0, stream>>>(Wf1, Wt1, 512, 256);
  transpose_w_kernel<<<((int)WT1 + 255) / 256, 256, 0, stream>>>(Wb1, Wt1 + WT1, 512, 256);

  for (int t = 0; t < T; ++t) {
    const int pi = t & 1, po = 1 - pi;
    step_kernel<<<768, 512, 0, stream>>>(
        feat0 + (size_t)t * SZ0, feat1 + (size_t)t * SZ1, mask + t * 8,
        Wt0, Wt1, bf0, bb0, bf1, bb1,
        h0 + (size_t)pi * 2 * SZ0, h0 + (size_t)po * 2 * SZ0, c0,
        h1 + (size_t)pi * 2 * SZ1, h1 + (size_t)po * 2 * SZ1, c1);
  }

  // T=16 is even -> final states live in buf 0
  float* out = (float*)d_out;
  combine_kernel<<<((int)SZ0 + 255) / 256, 256, 0, stream>>>(h0, h0 + SZ0, out, (int)SZ0);
  combine_kernel<<<((int)SZ1 + 255) / 256, 256, 0, stream>>>(h1, h1 + SZ1, out + SZ0, (int)SZ1);
}